// Round 3
// baseline (16347.122 us; speedup 1.0000x reference)
//
#include <hip/hip_runtime.h>

#define T_   512
#define B_   64
#define E_   256
#define H_   768
#define V_   5000
#define G4H  3072

typedef __attribute__((ext_vector_type(8))) short bf16x8;
typedef __attribute__((ext_vector_type(4))) float f32x4;

__device__ __forceinline__ unsigned short f2bf(float x) {
  unsigned u = __float_as_uint(x);
  u += 0x7fff + ((u >> 16) & 1);               // round-to-nearest-even
  return (unsigned short)(u >> 16);
}
__device__ __forceinline__ float bf2f(unsigned short h) {
  return __uint_as_float(((unsigned)h) << 16);
}
__device__ __forceinline__ void gl_lds16(const void* g, void* l) {
  __builtin_amdgcn_global_load_lds(
      (const __attribute__((address_space(1))) unsigned int*)g,
      (__attribute__((address_space(3))) unsigned int*)l, 16, 0, 0);
}
__device__ __forceinline__ float sigm(float x) { return 1.f / (1.f + __expf(-x)); }
__device__ __forceinline__ float tanh_(float x) { return 1.f - 2.f / (1.f + __expf(2.f * x)); }

// ---------------------------------------------------------------------------
__global__ __launch_bounds__(256) void bias_sum_kernel(const float* __restrict__ b_ih,
                                                       const float* __restrict__ b_hh,
                                                       float* __restrict__ bias) {
  int i = blockIdx.x * 256 + threadIdx.x;
  if (i < G4H) bias[i] = b_ih[i] + b_hh[i];
}

// f32 [Rin][K] -> bf16 [Rout][2K] as [hi | lo]; rows >= Rin zero-padded.
__global__ __launch_bounds__(256) void conv_split(const float* __restrict__ in,
                                                  unsigned short* __restrict__ out,
                                                  int Rin, int Rout, int K) {
  int total = Rout * K;
  for (int i = blockIdx.x * 256 + threadIdx.x; i < total; i += gridDim.x * 256) {
    int r = i / K, k = i - r * K;
    float v = (r < Rin) ? in[(size_t)r * K + k] : 0.f;
    unsigned short hi = f2bf(v);
    out[(size_t)r * 2 * K + k] = hi;
    out[(size_t)r * 2 * K + K + k] = f2bf(v - bf2f(hi));
  }
}

// ---------------------------------------------------------------------------
// bf16 MFMA GEMM (m97 structure): C[M][N](f32) = A[.][ldA] · B[.][ldB]^T + bias
// 128x128 tile, BK=32, 4 waves each owning a 64x64 quadrant (4x4 of 16x16x32).
// k-region remap: src_k = kbase >= wrap ? kbase - wrap : kbase  (split-bf16 3-term).
// ---------------------------------------------------------------------------
__global__ __launch_bounds__(256) void gemm_bf16_mfma(
    const unsigned short* __restrict__ A, int ldA, int a_wrap,
    const unsigned short* __restrict__ B, int ldB, int b_wrap,
    const float* __restrict__ bias, float* __restrict__ C,
    int M, int N, int NB, int KP) {
  __shared__ __align__(16) unsigned short a_lds[128 * 32];
  __shared__ __align__(16) unsigned short b_lds[128 * 32];
  const int tid = threadIdx.x;
  const int lane = tid & 63;
  const int w = __builtin_amdgcn_readfirstlane(tid >> 6);
  const int wr = w >> 1, wc = w & 1;
  const int m0 = blockIdx.y * 128;
  const int n0 = blockIdx.x * 128;

  f32x4 acc[4][4];
#pragma unroll
  for (int m = 0; m < 4; m++)
#pragma unroll
    for (int n = 0; n < 4; n++) acc[m][n] = (f32x4){0.f, 0.f, 0.f, 0.f};

  const int nk = KP / 32;
  for (int kt = 0; kt < nk; kt++) {
    int kbase = kt * 32;
    int ak = kbase >= a_wrap ? kbase - a_wrap : kbase;
    int bk = kbase >= b_wrap ? kbase - b_wrap : kbase;
    __syncthreads();
#pragma unroll
    for (int p = 0; p < 2; p++) {
      int idx = (p << 8) + tid;                 // 0..511
      int row = idx >> 2, kg = (idx & 3) << 3;  // kg in bf16 elems
      int ar = m0 + row; if (ar >= M) ar = M - 1;
      gl_lds16(A + (size_t)ar * ldA + ak + kg, (char*)a_lds + idx * 16);
      int br = n0 + row; if (br >= NB) br = NB - 1;
      gl_lds16(B + (size_t)br * ldB + bk + kg, (char*)b_lds + idx * 16);
    }
    __syncthreads();

    bf16x8 aF[4], bF[4];
#pragma unroll
    for (int m = 0; m < 4; m++)
      aF[m] = *(const bf16x8*)&a_lds[(wr * 64 + m * 16 + (lane & 15)) * 32 + (lane >> 4) * 8];
#pragma unroll
    for (int n = 0; n < 4; n++)
      bF[n] = *(const bf16x8*)&b_lds[(wc * 64 + n * 16 + (lane & 15)) * 32 + (lane >> 4) * 8];
#pragma unroll
    for (int m = 0; m < 4; m++)
#pragma unroll
      for (int n = 0; n < 4; n++)
        acc[m][n] = __builtin_amdgcn_mfma_f32_16x16x32_bf16(aF[m], bF[n], acc[m][n], 0, 0, 0);
  }

  // C/D layout: col = lane&15, row = (lane>>4)*4 + reg  [m89/m91 verified]
#pragma unroll
  for (int m = 0; m < 4; m++) {
    int row0 = m0 + wr * 64 + m * 16 + (lane >> 4) * 4;
#pragma unroll
    for (int n = 0; n < 4; n++) {
      int col = n0 + wc * 64 + n * 16 + (lane & 15);
      if (col < N) {
        float bv = bias ? bias[col] : 0.f;
#pragma unroll
        for (int reg = 0; reg < 4; reg++) {
          int r = row0 + reg;
          if (r < M) C[(size_t)r * N + col] = acc[m][n][reg] + bv;
        }
      }
    }
  }
}

// ---------------------------------------------------------------------------
// LSTM step v2: 192 blocks x 256 threads. Block owns 4 j-cols (all 4 gates).
// wave w: cpair = w&1 -> 2 cols, kh = w>>1 -> k-half [kh*384, kh*384+384).
// lane = batch b. W_hh rows read via scalar pipe (uniform addresses -> s_load,
// SGPR FMA operands, zero LDS cost). h chunks staged via global_load_lds with
// pre-swizzled source (linear LDS dest, XOR-swizzled read: conflict-free).
// Partial k-sums combined in LDS; epilogue does gates+state+h/bf16 writes.
// ---------------------------------------------------------------------------
__global__ __launch_bounds__(256) void lstm_step2(
    const float* __restrict__ h_in, float* __restrict__ h_out,
    float* __restrict__ c_st, const float* __restrict__ eproj,
    const int* __restrict__ x, const float* __restrict__ W_hh,
    unsigned short* __restrict__ Ah, int ldAh, int write_lo, int t) {
  __shared__ __align__(16) float h_lds[2][64][128];  // 64 KB, reused as pacc
  const int tid = threadIdx.x;
  const int lane = tid & 63;
  const int w = __builtin_amdgcn_readfirstlane(tid >> 6);
  const int kh = w >> 1, cpair = w & 1;
  const int jb = blockIdx.x * 4;
  const int rbase = __builtin_amdgcn_readfirstlane(jb + cpair * 2);
  const int kstart = __builtin_amdgcn_readfirstlane(kh * 384);

  float acc[2][4];
#pragma unroll
  for (int c = 0; c < 2; c++)
#pragma unroll
    for (int g = 0; g < 4; g++) acc[c][g] = 0.f;

  for (int i = 0; i < 3; i++) {
    __syncthreads();
    // stage chunk i of both k-halves: LDS[half][b][q'] = h[b][half*384+i*128+(q'^(b&7))*4 ..+4)
#pragma unroll
    for (int p = 0; p < 16; p++) {
      int half = p >> 3;
      int idx8 = ((p & 7) << 8) + tid;  // 0..2047
      int b = idx8 >> 5, qp = idx8 & 31;
      int q = qp ^ (b & 7);
      gl_lds16(h_in + (size_t)b * H_ + half * 384 + i * 128 + q * 4,
               (char*)&h_lds[0][0][0] + half * 32768 + idx8 * 16);
    }
    __syncthreads();
    const int kg0 = kstart + i * 128;
#pragma unroll 2
    for (int q = 0; q < 32; q++) {
      float4 hv = *(const float4*)&h_lds[kh][lane][(q ^ (lane & 7)) << 2];
      const int ko = kg0 + q * 4;
#pragma unroll
      for (int c = 0; c < 2; c++)
#pragma unroll
        for (int g = 0; g < 4; g++) {
          const float* wp = W_hh + (size_t)(g * H_ + rbase + c) * H_ + ko;
          acc[c][g] += hv.x * wp[0] + hv.y * wp[1] + hv.z * wp[2] + hv.w * wp[3];
        }
    }
  }

  __syncthreads();
  float* pacc = &h_lds[0][0][0];  // [wave][lane][8]
#pragma unroll
  for (int c = 0; c < 2; c++)
#pragma unroll
    for (int g = 0; g < 4; g++) pacc[(w * 64 + lane) * 8 + c * 4 + g] = acc[c][g];
  __syncthreads();

  // epilogue: thread -> (b = tid>>2, jloc = tid&3)
  const int b = tid >> 2, jloc = tid & 3;
  const int cpe = jloc >> 1, ci = jloc & 1;
  const int jcol = jb + jloc;
  const int xid = x[b * T_ + t];
  const float* ep = eproj + (size_t)xid * G4H;
  float gates[4];
#pragma unroll
  for (int g = 0; g < 4; g++)
    gates[g] = pacc[((0 * 2 + cpe) * 64 + b) * 8 + ci * 4 + g] +
               pacc[((1 * 2 + cpe) * 64 + b) * 8 + ci * 4 + g] +
               ep[g * H_ + jcol];
  float ig = sigm(gates[0]);
  float fg = sigm(gates[1]);
  float gg = tanh_(gates[2]);
  float og = sigm(gates[3]);
  float cp = c_st[b * H_ + jcol];
  float cn = fg * cp + ig * gg;
  float hn = og * tanh_(cn);
  c_st[b * H_ + jcol] = cn;
  h_out[b * H_ + jcol] = hn;
  size_t arow = (size_t)(b * T_ + t) * ldAh;
  unsigned short hi = f2bf(hn);
  Ah[arow + jcol] = hi;
  if (write_lo) Ah[arow + H_ + jcol] = f2bf(hn - bf2f(hi));
}

// ---------------------------------------------------------------------------
extern "C" void kernel_launch(void* const* d_in, const int* in_sizes, int n_in,
                              void* d_out, int out_size, void* d_ws, size_t ws_size,
                              hipStream_t stream) {
  const int*   x     = (const int*)d_in[0];
  const float* embed = (const float*)d_in[2];
  const float* W_ih  = (const float*)d_in[3];
  const float* W_hh  = (const float*)d_in[4];
  const float* b_ih  = (const float*)d_in[5];
  const float* b_hh  = (const float*)d_in[6];
  const float* fc_w  = (const float*)d_in[7];
  const float* fc_b  = (const float*)d_in[8];
  float* out = (float*)d_out;

  char* ws = (char*)d_ws;
  size_t off = 0;
  auto alloc = [&](size_t bytes) {
    char* p = ws + off;
    off = (off + bytes + 255) & ~(size_t)255;
    return p;
  };
  float* eproj = (float*)alloc((size_t)V_ * G4H * 4);      // 61.44 MB
  float* hb0   = (float*)alloc((size_t)B_ * H_ * 4);
  float* hb1   = (float*)alloc((size_t)B_ * H_ * 4);
  float* c_st  = (float*)alloc((size_t)B_ * H_ * 4);
  float* bias  = (float*)alloc(G4H * 4);
  unsigned short* emb2 = (unsigned short*)alloc((size_t)V_ * 512 * 2);
  unsigned short* wih2 = (unsigned short*)alloc((size_t)G4H * 512 * 2);
  unsigned short* bfc2 = (unsigned short*)alloc((size_t)5120 * 1536 * 2);
  size_t fixed = off;
  int full = (fixed + (size_t)32768 * 1536 * 2 + 256 <= ws_size);
  int ldAh = full ? 1536 : 768;
  unsigned short* Ah = (unsigned short*)alloc((size_t)32768 * ldAh * 2);
  if (off > ws_size) return;  // fail loudly (out stays poisoned)

  hipMemsetAsync(hb0, 0, (size_t)B_ * H_ * 4, stream);
  hipMemsetAsync(c_st, 0, (size_t)B_ * H_ * 4, stream);
  bias_sum_kernel<<<(G4H + 255) / 256, 256, 0, stream>>>(b_ih, b_hh, bias);
  conv_split<<<1024, 256, 0, stream>>>(embed, emb2, V_, V_, E_);
  conv_split<<<1024, 256, 0, stream>>>(W_ih, wih2, G4H, G4H, E_);
  conv_split<<<2048, 256, 0, stream>>>(fc_w, bfc2, V_, 5120, H_);

  // eproj = embed @ W_ih^T + (b_ih+b_hh): split-bf16 3-term, KP = 3*256
  gemm_bf16_mfma<<<dim3(G4H / 128, (V_ + 127) / 128), 256, 0, stream>>>(
      emb2, 512, 512, wih2, 512, 256, bias, eproj, V_, G4H, G4H, 768);

  float* hbuf[2] = {hb0, hb1};
  for (int t = 0; t < T_; t++)
    lstm_step2<<<H_ / 4, 256, 0, stream>>>(hbuf[t & 1], hbuf[(t + 1) & 1], c_st,
                                           eproj, x, W_hh, Ah, ldAh, full, t);

  // out = h @ fc_w^T + fc_b: split-bf16 (3-term if ws allows, else 2-term)
  if (full)
    gemm_bf16_mfma<<<dim3(5120 / 128, 32768 / 128), 256, 0, stream>>>(
        Ah, 1536, 1536, bfc2, 1536, 768, fc_b, out, 32768, V_, 5120, 2304);
  else
    gemm_bf16_mfma<<<dim3(5120 / 128, 32768 / 128), 256, 0, stream>>>(
        Ah, 768, 768, bfc2, 1536, 1536, fc_b, out, 32768, V_, 5120, 1536);
}